// Round 3
// baseline (200.059 us; speedup 1.0000x reference)
//
#include <hip/hip_runtime.h>

// TripletColbertLoss on MFMA: q (B,Q,D), p/n (B,K,D) fp32 -> scalar.
// loss = relu(0.2 + neg - pos), score = sum_{b,q} max_k q.d
// B=256 Q=256 K=512 D=128.
//
// R5: schedule fix. R3 (2 waves/SIMD) == R4 (3-4 waves/SIMD, 2x LDS traffic)
// == 67.5us proves the limit is the 2-phase stage->barrier->compute structure
// (m233 pathology), not occupancy / LDS BW. This version moves the stage of
// tile t+1 (convert + ds_write) INTO the MFMA region of tile t, one barrier
// per tile at the END of the body. Convert VALU + ds_writes + global prefetch
// interleave with MFMAs (independent chains); prefetch has a full MFMA phase
// to land before the barrier's vmcnt drain.
// Blocking unchanged from R4: 512 thr, 8 waves x 32 q-rows, 16x16x32 MFMA,
// bf16 3-term truncation split, BSTR=136 LDS layout (all verified).

#define MARGIN   0.2f
#define Bn       256
#define Qn       256
#define Kn       512
#define Dn       128
#define TN       32            // docs per tile
#define NT       (Kn / TN)     // 16 tiles
#define BSTR     136           // doc stride (bf16 units): 272 B, 16B-aligned
#define NTHREADS 512

typedef __attribute__((ext_vector_type(8))) short short8;
typedef __attribute__((ext_vector_type(4))) short short4v;
typedef __attribute__((ext_vector_type(4))) float f32x4;

// Truncation split: x = hi + lo (both bf16 by bit-truncation). hi err <= 2^-8
// is captured exactly by lo; lo trunc err ~2^-17 of x. Cheap: shifts only.
__device__ __forceinline__ void split_trunc(float x, unsigned short& hi, unsigned short& lo) {
    unsigned int u = __float_as_uint(x);
    hi = (unsigned short)(u >> 16);
    float l = x - __uint_as_float(u & 0xFFFF0000u);
    lo = (unsigned short)(__float_as_uint(l) >> 16);
}

__global__ __launch_bounds__(NTHREADS, 4)
void colbert_pass_kernel(const float* __restrict__ qg,
                         const float* __restrict__ pg,
                         const float* __restrict__ ng,
                         double* __restrict__ sum_ws) {
    __shared__ short Bs[2][2][TN * BSTR];   // [buf][hi/lo][doc*BSTR + dim]  34816 B
    __shared__ float part[8];

    const int tid  = threadIdx.x;
    const int w    = tid >> 6;              // 8 waves
    const int lane = tid & 63;
    const int l16  = lane & 15;
    const int quad = lane >> 4;
    const int b    = blockIdx.x;
    const int pass = blockIdx.y;            // 0 -> p (+), 1 -> n (-)

    const float* docb = (pass ? ng : pg) + (size_t)b * Kn * Dn;

    // LDS staging addresses for this thread (reused every tile).
    const int cdoc = tid >> 5;              // 512 thr: thread covers (tid, tid+512)
    const int cd4  = tid & 31;

    // Prologue: tile0 + tile1 global loads in flight before A-conversion VALU.
    float4 pre2[2][2];                      // [parity][k] ; pre2[(t+1)&1] = tile t+1
    {
        const float4* s4 = (const float4*)docb;
#pragma unroll
        for (int k = 0; k < 2; ++k) pre2[0][k] = s4[tid + 512 * k];
        const float4* s41 = (const float4*)(docb + (size_t)TN * Dn);
#pragma unroll
        for (int k = 0; k < 2; ++k) pre2[1][k] = s41[tid + 512 * k];
    }

    // ---- A fragments: 32 q-rows per wave (mi = 0,1 -> 16 rows each).
    // 16x16x32 A layout: lane holds A[m = l16][k = quad*8 + j], j=0..7.
    short8 Ahi[2][4], Alo[2][4];            // [mi][ks]
    {
        const float* qb = qg + (size_t)b * Qn * Dn;
#pragma unroll
        for (int mi = 0; mi < 2; ++mi)
#pragma unroll
            for (int ks = 0; ks < 4; ++ks) {
                const float* src = qb + (size_t)(w * 32 + mi * 16 + l16) * Dn
                                      + ks * 32 + quad * 8;
                float4 v0 = *(const float4*)src;
                float4 v1 = *(const float4*)(src + 4);
                float x[8] = {v0.x, v0.y, v0.z, v0.w, v1.x, v1.y, v1.z, v1.w};
#pragma unroll
                for (int j = 0; j < 8; ++j) {
                    unsigned short h, l;
                    split_trunc(x[j], h, l);
                    Ahi[mi][ks][j] = (short)h;
                    Alo[mi][ks][j] = (short)l;
                }
            }
    }

    // Convert tile 0 into Bs[0].
#pragma unroll
    for (int k = 0; k < 2; ++k) {
        int i   = tid + 512 * k;
        int doc = i >> 5;
        int d4  = i & 31;
        float4 v = pre2[0][k];
        float x[4] = {v.x, v.y, v.z, v.w};
        short4v hi, lo;
#pragma unroll
        for (int j = 0; j < 4; ++j) {
            unsigned short h, l;
            split_trunc(x[j], h, l);
            hi[j] = (short)h;
            lo[j] = (short)l;
        }
        *(short4v*)&Bs[0][0][doc * BSTR + d4 * 4] = hi;
        *(short4v*)&Bs[0][1][doc * BSTR + d4 * 4] = lo;
    }
    __syncthreads();

    float maxv[2][4];                       // [mi][reg] running row-max
#pragma unroll
    for (int mi = 0; mi < 2; ++mi)
#pragma unroll
        for (int r = 0; r < 4; ++r) maxv[mi][r] = -3e38f;

    for (int t = 0; t < NT; ++t) {
        const int cur = t & 1;

        // Issue global prefetch of tile t+2 early: a full MFMA phase to land.
        if (t + 2 < NT) {
            const float4* s4 = (const float4*)(docb + (size_t)(t + 2) * TN * Dn);
#pragma unroll
            for (int k = 0; k < 2; ++k) pre2[cur][k] = s4[tid + 512 * k];
        }

        f32x4 acc[2][2];                    // [mi][ni]
#pragma unroll
        for (int mi = 0; mi < 2; ++mi)
#pragma unroll
            for (int ni = 0; ni < 2; ++ni) acc[mi][ni] = (f32x4){0.f, 0.f, 0.f, 0.f};

        // --- ni = 0: reads + 24 MFMAs from Bs[cur] ---
        {
#pragma unroll
            for (int ks = 0; ks < 4; ++ks) {
                int off = l16 * BSTR + ks * 32 + quad * 8;
                short8 bh = *(const short8*)&Bs[cur][0][off];
                short8 bl = *(const short8*)&Bs[cur][1][off];
                acc[0][0] = __builtin_amdgcn_mfma_f32_16x16x32_bf16(
                    Ahi[0][ks], bh, acc[0][0], 0, 0, 0);
                acc[1][0] = __builtin_amdgcn_mfma_f32_16x16x32_bf16(
                    Ahi[1][ks], bh, acc[1][0], 0, 0, 0);
                acc[0][0] = __builtin_amdgcn_mfma_f32_16x16x32_bf16(
                    Alo[0][ks], bh, acc[0][0], 0, 0, 0);
                acc[1][0] = __builtin_amdgcn_mfma_f32_16x16x32_bf16(
                    Alo[1][ks], bh, acc[1][0], 0, 0, 0);
                acc[0][0] = __builtin_amdgcn_mfma_f32_16x16x32_bf16(
                    Ahi[0][ks], bl, acc[0][0], 0, 0, 0);
                acc[1][0] = __builtin_amdgcn_mfma_f32_16x16x32_bf16(
                    Ahi[1][ks], bl, acc[1][0], 0, 0, 0);
            }
        }

        // --- stage tile t+1 into Bs[cur^1] (overlaps with MFMAs above/below) ---
        if (t + 1 < NT) {
#pragma unroll
            for (int k = 0; k < 2; ++k) {
                float4 v = pre2[(t + 1) & 1][k];
                int doc = cdoc + 16 * k;
                float x[4] = {v.x, v.y, v.z, v.w};
                short4v hi, lo;
#pragma unroll
                for (int j = 0; j < 4; ++j) {
                    unsigned short h, l;
                    split_trunc(x[j], h, l);
                    hi[j] = (short)h;
                    lo[j] = (short)l;
                }
                *(short4v*)&Bs[cur ^ 1][0][doc * BSTR + cd4 * 4] = hi;
                *(short4v*)&Bs[cur ^ 1][1][doc * BSTR + cd4 * 4] = lo;
            }
        }

        // --- ni = 1: reads + 24 MFMAs from Bs[cur] ---
        {
#pragma unroll
            for (int ks = 0; ks < 4; ++ks) {
                int off = (16 + l16) * BSTR + ks * 32 + quad * 8;
                short8 bh = *(const short8*)&Bs[cur][0][off];
                short8 bl = *(const short8*)&Bs[cur][1][off];
                acc[0][1] = __builtin_amdgcn_mfma_f32_16x16x32_bf16(
                    Ahi[0][ks], bh, acc[0][1], 0, 0, 0);
                acc[1][1] = __builtin_amdgcn_mfma_f32_16x16x32_bf16(
                    Ahi[1][ks], bh, acc[1][1], 0, 0, 0);
                acc[0][1] = __builtin_amdgcn_mfma_f32_16x16x32_bf16(
                    Alo[0][ks], bh, acc[0][1], 0, 0, 0);
                acc[1][1] = __builtin_amdgcn_mfma_f32_16x16x32_bf16(
                    Alo[1][ks], bh, acc[1][1], 0, 0, 0);
                acc[0][1] = __builtin_amdgcn_mfma_f32_16x16x32_bf16(
                    Ahi[0][ks], bl, acc[0][1], 0, 0, 0);
                acc[1][1] = __builtin_amdgcn_mfma_f32_16x16x32_bf16(
                    Ahi[1][ks], bl, acc[1][1], 0, 0, 0);
            }
        }

        // C/D layout: col(doc)=l16, row=quad*4+reg
#pragma unroll
        for (int mi = 0; mi < 2; ++mi)
#pragma unroll
            for (int r = 0; r < 4; ++r)
                maxv[mi][r] = fmaxf(maxv[mi][r], fmaxf(acc[mi][0][r], acc[mi][1][r]));

        // Single barrier per tile: orders this tile's reads before t+2's writes
        // and t+1's writes before t+1's reads.
        __syncthreads();
    }

    // max over the 16 doc-column lanes
#pragma unroll
    for (int off = 1; off < 16; off <<= 1)
#pragma unroll
        for (int mi = 0; mi < 2; ++mi)
#pragma unroll
            for (int r = 0; r < 4; ++r)
                maxv[mi][r] = fmaxf(maxv[mi][r], __shfl_xor(maxv[mi][r], off));

    float s = 0.f;
#pragma unroll
    for (int mi = 0; mi < 2; ++mi)
#pragma unroll
        for (int r = 0; r < 4; ++r) s += maxv[mi][r];
    if (l16 != 0) s = 0.f;                  // one copy per quad
    s += __shfl_xor(s, 16);                 // combine the 4 quads
    s += __shfl_xor(s, 32);
    if (lane == 0) part[w] = s;
    __syncthreads();
    if (tid == 0) {
        double t = 0.0;
#pragma unroll
        for (int i = 0; i < 8; ++i) t += (double)part[i];
        atomicAdd(sum_ws, pass ? -t : t);   // S = pos - neg, exact in fp64
    }
}

__global__ void finalize_kernel(const double* __restrict__ sum_ws,
                                float* __restrict__ out) {
    out[0] = fmaxf(0.0f, MARGIN - (float)sum_ws[0]);
}

extern "C" void kernel_launch(void* const* d_in, const int* in_sizes, int n_in,
                              void* d_out, int out_size, void* d_ws, size_t ws_size,
                              hipStream_t stream) {
    const float* q = (const float*)d_in[0];
    const float* p = (const float*)d_in[1];
    const float* n = (const float*)d_in[2];
    float* out = (float*)d_out;
    double* ws = (double*)d_ws;

    hipMemsetAsync(ws, 0, sizeof(double), stream);  // ws re-poisoned each call

    colbert_pass_kernel<<<dim3(Bn, 2), NTHREADS, 0, stream>>>(q, p, n, ws);
    finalize_kernel<<<1, 1, 0, stream>>>(ws, out);
}

// Round 4
// 188.640 us; speedup vs baseline: 1.0605x; 1.0605x over previous
//
#include <hip/hip_runtime.h>

// TripletColbertLoss on MFMA: q (B,Q,D), p/n (B,K,D) fp32 -> scalar.
// loss = relu(0.2 + neg - pos), score = sum_{b,q} max_k q.d
// B=256 Q=256 K=512 D=128.
//
// R6: R5's schedule (stage tile t+1 inside tile t's MFMA region, single
// end-of-tile barrier) was sabotaged by rule #20: pre2[cur][k] with runtime
// cur went to SCRATCH (WRITE_SIZE 16KB -> 35.8MB, MfmaUtil 22%). This
// version unrolls the tile loop by 2 so every prefetch-register and LDS-buf
// index is a compile-time literal: named preE/preO buffers, Bs[0]/Bs[1] by
// constant. Schedule per tile: prefetch(t+2) -> ni=0 MFMA -> stage(t+1) ->
// ni=1 MFMA -> barrier.
// Blocking unchanged: 512 thr, 8 waves x 32 q-rows, 16x16x32 MFMA, bf16
// 3-term truncation split, BSTR=136 LDS layout (all verified).

#define MARGIN   0.2f
#define Bn       256
#define Qn       256
#define Kn       512
#define Dn       128
#define TN       32            // docs per tile
#define NT       (Kn / TN)     // 16 tiles
#define BSTR     136           // doc stride (bf16 units): 272 B, 16B-aligned
#define NTHREADS 512

typedef __attribute__((ext_vector_type(8))) short short8;
typedef __attribute__((ext_vector_type(4))) short short4v;
typedef __attribute__((ext_vector_type(4))) float f32x4;

// Truncation split: x = hi + lo (both bf16 by bit-truncation). hi err <= 2^-8
// is captured exactly by lo; lo trunc err ~2^-17 of x. Cheap: shifts only.
__device__ __forceinline__ void split_trunc(float x, unsigned short& hi, unsigned short& lo) {
    unsigned int u = __float_as_uint(x);
    hi = (unsigned short)(u >> 16);
    float l = x - __uint_as_float(u & 0xFFFF0000u);
    lo = (unsigned short)(__float_as_uint(l) >> 16);
}

// 24 MFMAs for one ni quadrant from Bs[CUR]; CUR/NI are literal constants.
#define MFMA_PHASE(CUR, NI)                                                    \
    {                                                                          \
        _Pragma("unroll")                                                      \
        for (int ks = 0; ks < 4; ++ks) {                                       \
            int off = ((NI) * 16 + l16) * BSTR + ks * 32 + quad * 8;           \
            short8 bh = *(const short8*)&Bs[CUR][0][off];                      \
            short8 bl = *(const short8*)&Bs[CUR][1][off];                      \
            acc[0][NI] = __builtin_amdgcn_mfma_f32_16x16x32_bf16(              \
                Ahi[0][ks], bh, acc[0][NI], 0, 0, 0);                          \
            acc[1][NI] = __builtin_amdgcn_mfma_f32_16x16x32_bf16(              \
                Ahi[1][ks], bh, acc[1][NI], 0, 0, 0);                          \
            acc[0][NI] = __builtin_amdgcn_mfma_f32_16x16x32_bf16(              \
                Alo[0][ks], bh, acc[0][NI], 0, 0, 0);                          \
            acc[1][NI] = __builtin_amdgcn_mfma_f32_16x16x32_bf16(              \
                Alo[1][ks], bh, acc[1][NI], 0, 0, 0);                          \
            acc[0][NI] = __builtin_amdgcn_mfma_f32_16x16x32_bf16(              \
                Ahi[0][ks], bl, acc[0][NI], 0, 0, 0);                          \
            acc[1][NI] = __builtin_amdgcn_mfma_f32_16x16x32_bf16(              \
                Ahi[1][ks], bl, acc[1][NI], 0, 0, 0);                          \
        }                                                                      \
    }

// Convert a prefetched tile (PRE = float4[2]) into Bs[DST]; DST literal.
#define STAGE(PRE, DST)                                                        \
    {                                                                          \
        _Pragma("unroll")                                                      \
        for (int k = 0; k < 2; ++k) {                                          \
            float4 v = PRE[k];                                                 \
            int doc = cdoc + 16 * k;                                           \
            float x[4] = {v.x, v.y, v.z, v.w};                                 \
            short4v hi, lo;                                                    \
            _Pragma("unroll")                                                  \
            for (int j = 0; j < 4; ++j) {                                      \
                unsigned short h, l;                                           \
                split_trunc(x[j], h, l);                                       \
                hi[j] = (short)h;                                              \
                lo[j] = (short)l;                                              \
            }                                                                  \
            *(short4v*)&Bs[DST][0][doc * BSTR + cd4 * 4] = hi;                 \
            *(short4v*)&Bs[DST][1][doc * BSTR + cd4 * 4] = lo;                 \
        }                                                                      \
    }

// Issue global loads of tile T into PRE (guarded).
#define PREFETCH(PRE, T)                                                       \
    if ((T) < NT) {                                                            \
        const float4* s4 = (const float4*)(docb + (size_t)(T) * TN * Dn);      \
        _Pragma("unroll")                                                      \
        for (int k = 0; k < 2; ++k) PRE[k] = s4[tid + 512 * k];                \
    }

#define UPDATE_MAX()                                                           \
    {                                                                          \
        _Pragma("unroll")                                                      \
        for (int mi = 0; mi < 2; ++mi)                                         \
            _Pragma("unroll")                                                  \
            for (int r = 0; r < 4; ++r)                                        \
                maxv[mi][r] = fmaxf(maxv[mi][r],                               \
                                    fmaxf(acc[mi][0][r], acc[mi][1][r]));      \
    }

__global__ __launch_bounds__(NTHREADS, 4)
void colbert_pass_kernel(const float* __restrict__ qg,
                         const float* __restrict__ pg,
                         const float* __restrict__ ng,
                         double* __restrict__ sum_ws) {
    __shared__ short Bs[2][2][TN * BSTR];   // [buf][hi/lo][doc*BSTR + dim]  34816 B
    __shared__ float part[8];

    const int tid  = threadIdx.x;
    const int w    = tid >> 6;              // 8 waves
    const int lane = tid & 63;
    const int l16  = lane & 15;
    const int quad = lane >> 4;
    const int b    = blockIdx.x;
    const int pass = blockIdx.y;            // 0 -> p (+), 1 -> n (-)

    const float* docb = (pass ? ng : pg) + (size_t)b * Kn * Dn;

    // LDS staging address for this thread (reused every tile).
    const int cdoc = tid >> 5;              // thread covers docs cdoc, cdoc+16
    const int cd4  = tid & 31;

    // Prologue: tile0 (-> preE) and tile1 (-> preO) loads in flight before
    // the A-conversion VALU burst.
    float4 preE[2], preO[2];
    {
        const float4* s4 = (const float4*)docb;
#pragma unroll
        for (int k = 0; k < 2; ++k) preE[k] = s4[tid + 512 * k];
        const float4* s41 = (const float4*)(docb + (size_t)TN * Dn);
#pragma unroll
        for (int k = 0; k < 2; ++k) preO[k] = s41[tid + 512 * k];
    }

    // ---- A fragments: 32 q-rows per wave (mi = 0,1 -> 16 rows each).
    // 16x16x32 A layout: lane holds A[m = l16][k = quad*8 + j], j=0..7.
    short8 Ahi[2][4], Alo[2][4];            // [mi][ks]
    {
        const float* qb = qg + (size_t)b * Qn * Dn;
#pragma unroll
        for (int mi = 0; mi < 2; ++mi)
#pragma unroll
            for (int ks = 0; ks < 4; ++ks) {
                const float* src = qb + (size_t)(w * 32 + mi * 16 + l16) * Dn
                                      + ks * 32 + quad * 8;
                float4 v0 = *(const float4*)src;
                float4 v1 = *(const float4*)(src + 4);
                float x[8] = {v0.x, v0.y, v0.z, v0.w, v1.x, v1.y, v1.z, v1.w};
#pragma unroll
                for (int j = 0; j < 8; ++j) {
                    unsigned short h, l;
                    split_trunc(x[j], h, l);
                    Ahi[mi][ks][j] = (short)h;
                    Alo[mi][ks][j] = (short)l;
                }
            }
    }

    // Stage tile 0 into Bs[0].
    STAGE(preE, 0)
    __syncthreads();

    float maxv[2][4];                       // [mi][reg] running row-max
#pragma unroll
    for (int mi = 0; mi < 2; ++mi)
#pragma unroll
        for (int r = 0; r < 4; ++r) maxv[mi][r] = -3e38f;

    // Main loop, unrolled x2 so all buffer indices are literals (rule #20).
    // Even body (tile t, reads Bs[0]): prefetch t+2 -> preE, stage t+1 -> Bs[1].
    // Odd  body (tile t+1, reads Bs[1]): prefetch t+3 -> preO, stage t+2 -> Bs[0].
    for (int t = 0; t < NT; t += 2) {
        {   // ---- even tile t
            f32x4 acc[2][2];
#pragma unroll
            for (int mi = 0; mi < 2; ++mi)
#pragma unroll
                for (int ni = 0; ni < 2; ++ni) acc[mi][ni] = (f32x4){0.f, 0.f, 0.f, 0.f};

            PREFETCH(preE, t + 2)
            MFMA_PHASE(0, 0)
            STAGE(preO, 1)                 // t+1 <= 15 always (t <= 14)
            MFMA_PHASE(0, 1)
            UPDATE_MAX()
            __syncthreads();
        }
        {   // ---- odd tile t+1
            f32x4 acc[2][2];
#pragma unroll
            for (int mi = 0; mi < 2; ++mi)
#pragma unroll
                for (int ni = 0; ni < 2; ++ni) acc[mi][ni] = (f32x4){0.f, 0.f, 0.f, 0.f};

            PREFETCH(preO, t + 3)
            MFMA_PHASE(1, 0)
            if (t + 2 < NT) STAGE(preE, 0)
            MFMA_PHASE(1, 1)
            UPDATE_MAX()
            __syncthreads();
        }
    }

    // max over the 16 doc-column lanes
#pragma unroll
    for (int off = 1; off < 16; off <<= 1)
#pragma unroll
        for (int mi = 0; mi < 2; ++mi)
#pragma unroll
            for (int r = 0; r < 4; ++r)
                maxv[mi][r] = fmaxf(maxv[mi][r], __shfl_xor(maxv[mi][r], off));

    float s = 0.f;
#pragma unroll
    for (int mi = 0; mi < 2; ++mi)
#pragma unroll
        for (int r = 0; r < 4; ++r) s += maxv[mi][r];
    if (l16 != 0) s = 0.f;                  // one copy per quad
    s += __shfl_xor(s, 16);                 // combine the 4 quads
    s += __shfl_xor(s, 32);
    if (lane == 0) part[w] = s;
    __syncthreads();
    if (tid == 0) {
        double t = 0.0;
#pragma unroll
        for (int i = 0; i < 8; ++i) t += (double)part[i];
        atomicAdd(sum_ws, pass ? -t : t);   // S = pos - neg, exact in fp64
    }
}

__global__ void finalize_kernel(const double* __restrict__ sum_ws,
                                float* __restrict__ out) {
    out[0] = fmaxf(0.0f, MARGIN - (float)sum_ws[0]);
}

extern "C" void kernel_launch(void* const* d_in, const int* in_sizes, int n_in,
                              void* d_out, int out_size, void* d_ws, size_t ws_size,
                              hipStream_t stream) {
    const float* q = (const float*)d_in[0];
    const float* p = (const float*)d_in[1];
    const float* n = (const float*)d_in[2];
    float* out = (float*)d_out;
    double* ws = (double*)d_ws;

    hipMemsetAsync(ws, 0, sizeof(double), stream);  // ws re-poisoned each call

    colbert_pass_kernel<<<dim3(Bn, 2), NTHREADS, 0, stream>>>(q, p, n, ws);
    finalize_kernel<<<1, 1, 0, stream>>>(ws, out);
}